// Round 2
// baseline (351.079 us; speedup 1.0000x reference)
//
#include <hip/hip_runtime.h>
#include <hip/hip_fp16.h>
#include <math.h>

#define S_LEN 2048
#define NHID  2048
#define D_HEAD 128
#define N_BH  32
#define EPS_Q 1e-8f

typedef _Float16 half8 __attribute__((ext_vector_type(8)));
typedef float floatx4 __attribute__((ext_vector_type(4)));

// ---------------- kernel 1: per-(bh,d) sums of k and v over s ----------------
__global__ void means_kernel(const float* __restrict__ kk, const float* __restrict__ vv,
                             float* __restrict__ ksum, float* __restrict__ vsum) {
  int blk = blockIdx.x;            // 32 bh * 16 chunks
  int bh = blk >> 4, chunk = blk & 15;
  int b = bh >> 4, h = bh & 15;
  int t = threadIdx.x;
  int d = t & 127, sub = t >> 7;
  const long base = ((long)b * S_LEN) * NHID + h * D_HEAD + d;
  int s0 = chunk * 128;
  float ks = 0.f, vs = 0.f;
  #pragma unroll 4
  for (int j = 0; j < 64; ++j) {
    long idx = base + (long)(s0 + j * 2 + sub) * NHID;
    ks += kk[idx];
    vs += vv[idx];
  }
  __shared__ float red[256];
  red[t] = ks; __syncthreads();
  if (t < 128) atomicAdd(&ksum[bh * D_HEAD + d], red[t] + red[t + 128]);
  __syncthreads();
  red[t] = vs; __syncthreads();
  if (t < 128) atomicAdd(&vsum[bh * D_HEAD + d], red[t] + red[t + 128]);
}

// ---------------- kernel 2: Q int8 quant (groups of 32 rows), stored as fp16 ints ----------------
__global__ void qquant_kernel(const float* __restrict__ q, _Float16* __restrict__ qq,
                              float* __restrict__ qscale) {
  int blk = blockIdx.x;            // 32 bh * 64 groups
  int bh = blk >> 6, g = blk & 63;
  int b = bh >> 4, h = bh & 15;
  int t = threadIdx.x;
  int s0 = g * 32;
  float vals[16];
  float am = 0.f;
  #pragma unroll
  for (int j = 0; j < 16; ++j) {
    int idx = t + j * 256;         // 0..4095
    int r = idx >> 7, d = idx & 127;
    float x = q[((long)(b * S_LEN + s0 + r)) * NHID + h * D_HEAD + d];
    vals[j] = x;
    am = fmaxf(am, fabsf(x));
  }
  __shared__ float red[256];
  red[t] = am; __syncthreads();
  for (int off = 128; off > 0; off >>= 1) {
    if (t < off) red[t] = fmaxf(red[t], red[t + off]);
    __syncthreads();
  }
  float scale = fmaxf(red[0] / 127.0f, EPS_Q);
  if (t == 0) qscale[bh * 64 + g] = scale;
  #pragma unroll
  for (int j = 0; j < 16; ++j) {
    int idx = t + j * 256;
    int r = idx >> 7, d = idx & 127;
    float xq = fminf(fmaxf(rintf(vals[j] / scale), -127.f), 127.f);
    qq[((long)bh * S_LEN + s0 + r) * D_HEAD + d] = (_Float16)xq;
  }
}

// ---------------- kernel 3: K smooth + int8 quant (groups of 64 rows) ----------------
__global__ void kquant_kernel(const float* __restrict__ kk, const float* __restrict__ ksum,
                              _Float16* __restrict__ kq, float* __restrict__ kscale) {
  int blk = blockIdx.x;            // 32 bh * 32 groups
  int bh = blk >> 5, g = blk & 31;
  int b = bh >> 4, h = bh & 15;
  int t = threadIdx.x;
  int s0 = g * 64;
  int d = t & 127;                 // idx = t + 256*j -> d constant per thread
  float mean = ksum[bh * D_HEAD + d] * (1.0f / 2048.0f);
  float vals[32];
  float am = 0.f;
  #pragma unroll
  for (int j = 0; j < 32; ++j) {
    int idx = t + j * 256;         // 0..8191
    int r = idx >> 7;
    float x = kk[((long)(b * S_LEN + s0 + r)) * NHID + h * D_HEAD + d] - mean;
    vals[j] = x;
    am = fmaxf(am, fabsf(x));
  }
  __shared__ float red[256];
  red[t] = am; __syncthreads();
  for (int off = 128; off > 0; off >>= 1) {
    if (t < off) red[t] = fmaxf(red[t], red[t + off]);
    __syncthreads();
  }
  float scale = fmaxf(red[0] / 127.0f, EPS_Q);
  if (t == 0) kscale[bh * 32 + g] = scale;
  #pragma unroll
  for (int j = 0; j < 32; ++j) {
    int idx = t + j * 256;
    int r = idx >> 7;
    float xq = fminf(fmaxf(rintf(vals[j] / scale), -127.f), 127.f);
    kq[((long)bh * S_LEN + s0 + r) * D_HEAD + d] = (_Float16)xq;
  }
}

// ---------------- kernel 4: V smooth -> fp16, transposed to [bh][d][s] ----------------
__global__ void vprep_kernel(const float* __restrict__ vv, const float* __restrict__ vsum,
                             _Float16* __restrict__ vt) {
  int blk = blockIdx.x;            // 32 bh * 32 s-tiles of 64
  int bh = blk >> 5, st = blk & 31;
  int b = bh >> 4, h = bh & 15;
  int t = threadIdx.x;
  int s0 = st * 64;
  __shared__ __align__(16) _Float16 tile[64][136];   // [s][d], padded
  int d = t & 127;
  float mean = vsum[bh * D_HEAD + d] * (1.0f / 2048.0f);
  #pragma unroll
  for (int j = 0; j < 32; ++j) {
    int idx = t + j * 256;
    int r = idx >> 7;
    float x = vv[((long)(b * S_LEN + s0 + r)) * NHID + h * D_HEAD + d] - mean;
    tile[r][d] = (_Float16)x;
  }
  __syncthreads();
  // transposed write: thread covers d-row (t>>1), s-half (t&1)*32
  int dr = t >> 1, sh = (t & 1) * 32;
  _Float16* dst = vt + ((long)bh * D_HEAD + dr) * S_LEN + s0 + sh;
  #pragma unroll
  for (int jo = 0; jo < 4; ++jo) {
    union { half8 v8; _Float16 h[8]; } u;
    #pragma unroll
    for (int ji = 0; ji < 8; ++ji) u.h[ji] = tile[sh + jo * 8 + ji][dr];
    *(half8*)(dst + jo * 8) = u.v8;
  }
}

// ---------------- kernel 5: fused sliding-window attention ----------------
__launch_bounds__(256, 2)
__global__ void attn_kernel(const _Float16* __restrict__ qq, const _Float16* __restrict__ kq,
                            const _Float16* __restrict__ vt,
                            const float* __restrict__ qscale, const float* __restrict__ kscale,
                            const float* __restrict__ vsum,
                            const int* __restrict__ wlp, const int* __restrict__ wrp,
                            float* __restrict__ out) {
  // XCD-swizzled mapping: each XCD keeps 4 bh's K/V hot in its L2
  int bid = blockIdx.x;
  int xcd = bid & 7, slot = bid >> 3;
  int bh = xcd * 4 + (slot >> 4);
  int qb = slot & 15;
  int b = bh >> 4, h = bh & 15;
  int q0 = qb * 128;

  int wl = *wlp; if (wl < 0) wl = S_LEN;
  int wr = *wrp; if (wr < 0) wr = S_LEN;

  int t = threadIdx.x;
  int wv = t >> 6;           // wave 0..3
  int lane = t & 63;
  int ln = lane & 15;
  int qd = lane >> 4;        // quad

  int r0 = q0 + wv * 32;     // this wave's first q row

  __shared__ __align__(16) _Float16 Kl[64 * 136];    // [key][d] padded (+16B)
  __shared__ __align__(16) _Float16 Vl[128 * 72];    // [d][key] padded (+16B)
  __shared__ __align__(16) _Float16 Pl[4][32 * 72];  // per-wave [qrow][key]

  // Q A-fragments resident in registers: A[m=lane&15][k=quad*8+j]
  half8 qa[2][4];
  {
    const _Float16* qbase = qq + ((long)bh * S_LEN) * D_HEAD;
    #pragma unroll
    for (int mb = 0; mb < 2; ++mb)
      #pragma unroll
      for (int ks = 0; ks < 4; ++ks)
        qa[mb][ks] = *(const half8*)(qbase + (long)(r0 + mb * 16 + ln) * D_HEAD + ks * 32 + qd * 8);
  }
  float qs = qscale[bh * 64 + (r0 >> 5)];

  float mrow[2][4], lrow[2][4];
  floatx4 oacc[2][8];
  #pragma unroll
  for (int mb = 0; mb < 2; ++mb)
    #pragma unroll
    for (int r = 0; r < 4; ++r) { mrow[mb][r] = -1e30f; lrow[mb][r] = 0.f; }
  #pragma unroll
  for (int mb = 0; mb < 2; ++mb)
    #pragma unroll
    for (int nd = 0; nd < 8; ++nd)
      oacc[mb][nd] = (floatx4){0.f, 0.f, 0.f, 0.f};

  int lo_wg = q0 - wl; if (lo_wg < 0) lo_wg = 0;
  int hi_wg = q0 + 127 + wr; if (hi_wg > S_LEN - 1) hi_wg = S_LEN - 1;
  int t_lo = lo_wg >> 6, t_hi = hi_wg >> 6;

  const float sm_scale = 0.08838834764831845f;  // 1/sqrt(128)
  const _Float16* kbase = kq + (long)bh * S_LEN * D_HEAD;
  const _Float16* vbase = vt + (long)bh * D_HEAD * S_LEN;

  for (int tt = t_lo; tt <= t_hi; ++tt) {
    int j0 = tt * 64;
    __syncthreads();   // previous tile's LDS reads done
    // stage K tile: 64 rows x 128 halfs, 16B chunks (16 chunks per row)
    #pragma unroll
    for (int c = 0; c < 4; ++c) {
      int chunk = t + c * 256;                       // 0..1023
      int row = chunk >> 4, off = (chunk & 15) * 8;  // row 0..63, off 0..120
      *(half8*)(Kl + row * 136 + off) = *(const half8*)(kbase + (long)(j0 + row) * D_HEAD + off);
    }
    // stage V tile (transposed layout): 128 d-rows x 64 halfs (8 chunks per row)
    #pragma unroll
    for (int c = 0; c < 4; ++c) {
      int chunk = t + c * 256;                       // 0..1023
      int dr = chunk >> 3, off = (chunk & 7) * 8;    // dr 0..127, off 0..56
      *(half8*)(Vl + dr * 72 + off) = *(const half8*)(vbase + (long)dr * S_LEN + j0 + off);
    }
    __syncthreads();

    // wave-uniform skip: tile entirely outside this wave's window
    if (j0 + 63 < r0 - wl || j0 > r0 + 31 + wr) continue;

    float ksc = kscale[bh * 32 + tt];
    float dscale = qs * ksc * sm_scale;
    bool need_mask = (j0 < r0 + 31 - wl) || (j0 + 63 > r0 + wr);

    // S = Q * K^T  (int8-exact in f16 MFMA, fp32 accumulate)
    floatx4 sacc[2][4];
    #pragma unroll
    for (int mb = 0; mb < 2; ++mb)
      #pragma unroll
      for (int nb = 0; nb < 4; ++nb) sacc[mb][nb] = (floatx4){0.f, 0.f, 0.f, 0.f};
    #pragma unroll
    for (int nb = 0; nb < 4; ++nb) {
      #pragma unroll
      for (int ks = 0; ks < 4; ++ks) {
        half8 bfr = *(const half8*)(Kl + (nb * 16 + ln) * 136 + ks * 32 + qd * 8);
        sacc[0][nb] = __builtin_amdgcn_mfma_f32_16x16x32_f16(qa[0][ks], bfr, sacc[0][nb], 0, 0, 0);
        sacc[1][nb] = __builtin_amdgcn_mfma_f32_16x16x32_f16(qa[1][ks], bfr, sacc[1][nb], 0, 0, 0);
      }
    }

    // dequant + mask + online softmax (C layout: col=lane&15, row=quad*4+reg)
    float p[2][4][4];
    float alpha[2][4];
    #pragma unroll
    for (int mb = 0; mb < 2; ++mb) {
      #pragma unroll
      for (int r = 0; r < 4; ++r) {
        int row = r0 + mb * 16 + qd * 4 + r;
        float sv[4];
        float mx = -1e30f;
        #pragma unroll
        for (int nb = 0; nb < 4; ++nb) {
          float s = sacc[mb][nb][r] * dscale;
          if (need_mask) {
            int col = j0 + nb * 16 + ln;
            bool ok = (row - col <= wl) && (col - row <= wr);
            s = ok ? s : -1e30f;
          }
          sv[nb] = s;
          mx = fmaxf(mx, s);
        }
        #pragma unroll
        for (int off = 1; off < 16; off <<= 1)
          mx = fmaxf(mx, __shfl_xor(mx, off, 64));
        float mnew = fmaxf(mrow[mb][r], mx);
        float a = __expf(mrow[mb][r] - mnew);
        float rs = 0.f;
        #pragma unroll
        for (int nb = 0; nb < 4; ++nb) {
          float pv = __expf(sv[nb] - mnew);
          p[mb][nb][r] = pv;
          rs += pv;
        }
        #pragma unroll
        for (int off = 1; off < 16; off <<= 1)
          rs += __shfl_xor(rs, off, 64);
        mrow[mb][r] = mnew;
        lrow[mb][r] = lrow[mb][r] * a + rs;
        alpha[mb][r] = a;
      }
    }

    // rescale O
    #pragma unroll
    for (int mb = 0; mb < 2; ++mb)
      #pragma unroll
      for (int nd = 0; nd < 8; ++nd) {
        floatx4 o = oacc[mb][nd];
        #pragma unroll
        for (int r = 0; r < 4; ++r) o[r] *= alpha[mb][r];
        oacc[mb][nd] = o;
      }

    // P: C layout -> fp16 -> per-wave LDS -> A-fragment layout
    _Float16* pw = Pl[wv];
    #pragma unroll
    for (int mb = 0; mb < 2; ++mb)
      #pragma unroll
      for (int nb = 0; nb < 4; ++nb)
        #pragma unroll
        for (int r = 0; r < 4; ++r)
          pw[(mb * 16 + qd * 4 + r) * 72 + nb * 16 + ln] = (_Float16)p[mb][nb][r];
    __threadfence_block();
    half8 pa[2][2];
    #pragma unroll
    for (int mb = 0; mb < 2; ++mb)
      #pragma unroll
      for (int ks = 0; ks < 2; ++ks)
        pa[mb][ks] = *(const half8*)(pw + (mb * 16 + ln) * 72 + ks * 32 + qd * 8);

    // O += P * Vhat
    #pragma unroll
    for (int nd = 0; nd < 8; ++nd) {
      #pragma unroll
      for (int ks = 0; ks < 2; ++ks) {
        half8 bfr = *(const half8*)(Vl + (nd * 16 + ln) * 72 + ks * 32 + qd * 8);
        oacc[0][nd] = __builtin_amdgcn_mfma_f32_16x16x32_f16(pa[0][ks], bfr, oacc[0][nd], 0, 0, 0);
        oacc[1][nd] = __builtin_amdgcn_mfma_f32_16x16x32_f16(pa[1][ks], bfr, oacc[1][nd], 0, 0, 0);
      }
    }
  }

  // epilogue: out = fp16(O/l) + v_mean
  float vm[8];
  #pragma unroll
  for (int nd = 0; nd < 8; ++nd)
    vm[nd] = vsum[bh * D_HEAD + nd * 16 + ln] * (1.0f / 2048.0f);
  float* obase = out + ((long)b * S_LEN) * NHID + h * D_HEAD;
  #pragma unroll
  for (int mb = 0; mb < 2; ++mb) {
    #pragma unroll
    for (int r = 0; r < 4; ++r) {
      int row = r0 + mb * 16 + qd * 4 + r;
      float linv = 1.0f / lrow[mb][r];
      #pragma unroll
      for (int nd = 0; nd < 8; ++nd) {
        float o16 = (float)(_Float16)(oacc[mb][nd][r] * linv);
        obase[(long)row * NHID + nd * 16 + ln] = o16 + vm[nd];
      }
    }
  }
}

extern "C" void kernel_launch(void* const* d_in, const int* in_sizes, int n_in,
                              void* d_out, int out_size, void* d_ws, size_t ws_size,
                              hipStream_t stream) {
  (void)in_sizes; (void)n_in; (void)out_size; (void)ws_size;
  const float* q = (const float*)d_in[0];
  const float* k = (const float*)d_in[1];
  const float* v = (const float*)d_in[2];
  const int* wl = (const int*)d_in[3];
  const int* wr = (const int*)d_in[4];
  float* out = (float*)d_out;

  char* ws = (char*)d_ws;
  size_t off = 0;
  const size_t tensz = (size_t)N_BH * S_LEN * D_HEAD * sizeof(_Float16);  // 16.78 MB
  _Float16* qq = (_Float16*)(ws + off); off += tensz;
  _Float16* kq = (_Float16*)(ws + off); off += tensz;
  _Float16* vt = (_Float16*)(ws + off); off += tensz;
  float* ksum   = (float*)(ws + off); off += N_BH * D_HEAD * sizeof(float);
  float* vsum   = (float*)(ws + off); off += N_BH * D_HEAD * sizeof(float);
  float* qscale = (float*)(ws + off); off += N_BH * 64 * sizeof(float);
  float* kscale = (float*)(ws + off); off += N_BH * 32 * sizeof(float);

  hipMemsetAsync(ksum, 0, 2 * N_BH * D_HEAD * sizeof(float), stream);
  means_kernel<<<512, 256, 0, stream>>>(k, v, ksum, vsum);
  qquant_kernel<<<2048, 256, 0, stream>>>(q, qq, qscale);
  kquant_kernel<<<1024, 256, 0, stream>>>(k, ksum, kq, kscale);
  vprep_kernel<<<1024, 256, 0, stream>>>(v, vsum, vt);
  attn_kernel<<<512, 256, 0, stream>>>(qq, kq, vt, qscale, kscale, vsum, wl, wr, out);
}

// Round 3
// 346.823 us; speedup vs baseline: 1.0123x; 1.0123x over previous
//
#include <hip/hip_runtime.h>
#include <hip/hip_fp16.h>
#include <math.h>

#define S_LEN 2048
#define NHID  2048
#define D_HEAD 128
#define N_BH  32
#define EPS_Q 1e-8f

typedef _Float16 half8 __attribute__((ext_vector_type(8)));
typedef _Float16 half4 __attribute__((ext_vector_type(4)));
typedef float floatx4 __attribute__((ext_vector_type(4)));

// ---------------- kernel 1: per-(bh,d) sums of k and v over s (float4, atomic) ----------------
__global__ void means_kernel(const float* __restrict__ kk, const float* __restrict__ vv,
                             float* __restrict__ ksum, float* __restrict__ vsum) {
  int blk = blockIdx.x;            // 32 bh * 16 chunks of 128 rows
  int bh = blk >> 4, chunk = blk & 15;
  int b = bh >> 4, h = bh & 15;
  int t = threadIdx.x;
  int d4 = t & 31, sg = t >> 5;    // d4: float4 column, sg: 8 row-subgroups
  int s0 = chunk * 128;
  const long base = ((long)(b * S_LEN + s0)) * NHID + h * D_HEAD + d4 * 4;
  floatx4 ks = {0.f,0.f,0.f,0.f}, vs = {0.f,0.f,0.f,0.f};
  #pragma unroll 4
  for (int j = 0; j < 16; ++j) {
    long idx = base + (long)(sg * 16 + j) * NHID;
    ks += *(const floatx4*)(kk + idx);
    vs += *(const floatx4*)(vv + idx);
  }
  __shared__ floatx4 red[256];
  red[t] = ks; __syncthreads();
  if (t < 128) red[t] += red[t + 128]; __syncthreads();
  if (t < 64)  red[t] += red[t + 64];  __syncthreads();
  if (t < 32) {
    floatx4 s = red[t] + red[t + 32];
    atomicAdd(&ksum[bh * D_HEAD + t * 4 + 0], s[0]);
    atomicAdd(&ksum[bh * D_HEAD + t * 4 + 1], s[1]);
    atomicAdd(&ksum[bh * D_HEAD + t * 4 + 2], s[2]);
    atomicAdd(&ksum[bh * D_HEAD + t * 4 + 3], s[3]);
  }
  __syncthreads();
  red[t] = vs; __syncthreads();
  if (t < 128) red[t] += red[t + 128]; __syncthreads();
  if (t < 64)  red[t] += red[t + 64];  __syncthreads();
  if (t < 32) {
    floatx4 s = red[t] + red[t + 32];
    atomicAdd(&vsum[bh * D_HEAD + t * 4 + 0], s[0]);
    atomicAdd(&vsum[bh * D_HEAD + t * 4 + 1], s[1]);
    atomicAdd(&vsum[bh * D_HEAD + t * 4 + 2], s[2]);
    atomicAdd(&vsum[bh * D_HEAD + t * 4 + 3], s[3]);
  }
}

// ---------------- kernel 2 (fused): qquant | kquant | vprep ----------------
// blk <  2048 : Q int8 quant, groups of 32 rows  (32 bh * 64 groups)
// blk <  3072 : K smooth + int8 quant, groups of 64 rows (32 bh * 32 groups)
// else        : V smooth -> fp16 transposed [bh][d][s] (32 bh * 32 s-tiles of 64)
__global__ void prep_kernel(const float* __restrict__ q, const float* __restrict__ k,
                            const float* __restrict__ v,
                            const float* __restrict__ ksum, const float* __restrict__ vsum,
                            _Float16* __restrict__ qq, _Float16* __restrict__ kq,
                            _Float16* __restrict__ vt,
                            float* __restrict__ qscale, float* __restrict__ kscale) {
  int blk = blockIdx.x;
  int t = threadIdx.x;
  __shared__ float red[256];
  __shared__ __align__(16) _Float16 tile[64 * 136];
  int d4 = t & 31, sg = t >> 5;

  if (blk < 2048) {
    // ---- Q quant: 32 rows x 128 d = 4 float4 per thread
    int bh = blk >> 6, g = blk & 63;
    int b = bh >> 4, h = bh & 15;
    int s0 = g * 32;
    const long gbase = ((long)(b * S_LEN + s0)) * NHID + h * D_HEAD + d4 * 4;
    floatx4 vals[4]; float am = 0.f;
    #pragma unroll
    for (int j = 0; j < 4; ++j) {
      int row = sg + j * 8;
      floatx4 x = *(const floatx4*)(q + gbase + (long)row * NHID);
      vals[j] = x;
      am = fmaxf(am, fmaxf(fmaxf(fabsf(x[0]), fabsf(x[1])), fmaxf(fabsf(x[2]), fabsf(x[3]))));
    }
    red[t] = am; __syncthreads();
    for (int off = 128; off > 0; off >>= 1) {
      if (t < off) red[t] = fmaxf(red[t], red[t + off]);
      __syncthreads();
    }
    float scale = fmaxf(red[0] / 127.0f, EPS_Q);
    if (t == 0) qscale[bh * 64 + g] = scale;
    float inv = 1.0f / scale;
    #pragma unroll
    for (int j = 0; j < 4; ++j) {
      int row = sg + j * 8;
      half4 hv;
      #pragma unroll
      for (int c = 0; c < 4; ++c)
        hv[c] = (_Float16)fminf(fmaxf(rintf(vals[j][c] * inv), -127.f), 127.f);
      *(half4*)(qq + ((long)bh * S_LEN + s0 + row) * D_HEAD + d4 * 4) = hv;
    }
  } else if (blk < 3072) {
    // ---- K smooth+quant: 64 rows x 128 d = 8 float4 per thread
    int bb = blk - 2048;
    int bh = bb >> 5, g = bb & 31;
    int b = bh >> 4, h = bh & 15;
    int s0 = g * 64;
    floatx4 mean = *(const floatx4*)(ksum + bh * D_HEAD + d4 * 4) * (1.0f / 2048.0f);
    const long gbase = ((long)(b * S_LEN + s0)) * NHID + h * D_HEAD + d4 * 4;
    floatx4 vals[8]; float am = 0.f;
    #pragma unroll
    for (int j = 0; j < 8; ++j) {
      int row = sg + j * 8;
      floatx4 x = *(const floatx4*)(k + gbase + (long)row * NHID) - mean;
      vals[j] = x;
      am = fmaxf(am, fmaxf(fmaxf(fabsf(x[0]), fabsf(x[1])), fmaxf(fabsf(x[2]), fabsf(x[3]))));
    }
    red[t] = am; __syncthreads();
    for (int off = 128; off > 0; off >>= 1) {
      if (t < off) red[t] = fmaxf(red[t], red[t + off]);
      __syncthreads();
    }
    float scale = fmaxf(red[0] / 127.0f, EPS_Q);
    if (t == 0) kscale[bh * 32 + g] = scale;
    float inv = 1.0f / scale;
    #pragma unroll
    for (int j = 0; j < 8; ++j) {
      int row = sg + j * 8;
      half4 hv;
      #pragma unroll
      for (int c = 0; c < 4; ++c)
        hv[c] = (_Float16)fminf(fmaxf(rintf(vals[j][c] * inv), -127.f), 127.f);
      *(half4*)(kq + ((long)bh * S_LEN + s0 + row) * D_HEAD + d4 * 4) = hv;
    }
  } else {
    // ---- V smooth -> transpose: 64 rows x 128 d
    int bb = blk - 3072;
    int bh = bb >> 5, st = bb & 31;
    int b = bh >> 4, h = bh & 15;
    int s0 = st * 64;
    floatx4 mean = *(const floatx4*)(vsum + bh * D_HEAD + d4 * 4) * (1.0f / 2048.0f);
    const long gbase = ((long)(b * S_LEN + s0)) * NHID + h * D_HEAD + d4 * 4;
    #pragma unroll
    for (int j = 0; j < 8; ++j) {
      int row = sg + j * 8;
      floatx4 x = *(const floatx4*)(v + gbase + (long)row * NHID) - mean;
      half4 hv = { (_Float16)x[0], (_Float16)x[1], (_Float16)x[2], (_Float16)x[3] };
      *(half4*)(tile + row * 136 + d4 * 4) = hv;
    }
    __syncthreads();
    int dr = t >> 1, sh = (t & 1) * 32;
    _Float16* dst = vt + ((long)bh * D_HEAD + dr) * S_LEN + s0 + sh;
    #pragma unroll
    for (int jo = 0; jo < 4; ++jo) {
      union { half8 v8; _Float16 h[8]; } u;
      #pragma unroll
      for (int ji = 0; ji < 8; ++ji) u.h[ji] = tile[(sh + jo * 8 + ji) * 136 + dr];
      *(half8*)(dst + jo * 8) = u.v8;
    }
  }
}

// ---------------- kernel 3: fused sliding-window attention ----------------
// 64 q-rows per block (4 waves x 16 rows), 64-key tiles, register prefetch.
__launch_bounds__(256, 3)
__global__ void attn_kernel(const _Float16* __restrict__ qq, const _Float16* __restrict__ kq,
                            const _Float16* __restrict__ vt,
                            const float* __restrict__ qscale, const float* __restrict__ kscale,
                            const float* __restrict__ vsum,
                            const int* __restrict__ wlp, const int* __restrict__ wrp,
                            float* __restrict__ out) {
  // XCD swizzle: 1024 blocks, each XCD owns 4 bh (K/V hot in its L2)
  int bid = blockIdx.x;
  int xcd = bid & 7, slot = bid >> 3;      // slot 0..127
  int bh = xcd * 4 + (slot >> 5);
  int qb = slot & 31;
  int b = bh >> 4, h = bh & 15;
  int q0 = qb * 64;

  int wl = *wlp; if (wl < 0) wl = S_LEN;
  int wr = *wrp; if (wr < 0) wr = S_LEN;

  int t = threadIdx.x;
  int wv = t >> 6;
  int lane = t & 63;
  int ln = lane & 15;
  int qd = lane >> 4;

  int r0 = q0 + wv * 16;                   // this wave's 16 q rows

  __shared__ __align__(16) _Float16 Kl[64 * 136];   // [key][d] padded
  __shared__ __align__(16) _Float16 Vl[128 * 72];   // [d][key] padded
  __shared__ __align__(16) _Float16 Pl[4][16 * 68]; // per-wave [qrow][key] padded

  // Q A-fragments resident: A[m=lane&15][k=quad*8+j]
  half8 qa[4];
  {
    const _Float16* qbase = qq + ((long)bh * S_LEN + r0 + ln) * D_HEAD;
    #pragma unroll
    for (int ks = 0; ks < 4; ++ks)
      qa[ks] = *(const half8*)(qbase + ks * 32 + qd * 8);
  }
  float qs = qscale[bh * 64 + (r0 >> 5)];

  float mrow[4], lrow[4];
  floatx4 oacc[8];
  #pragma unroll
  for (int r = 0; r < 4; ++r) { mrow[r] = -1e30f; lrow[r] = 0.f; }
  #pragma unroll
  for (int nd = 0; nd < 8; ++nd) oacc[nd] = (floatx4){0.f,0.f,0.f,0.f};

  int lo_wg = q0 - wl; if (lo_wg < 0) lo_wg = 0;
  int hi_wg = q0 + 63 + wr; if (hi_wg > S_LEN - 1) hi_wg = S_LEN - 1;
  int t_lo = lo_wg >> 6, t_hi = hi_wg >> 6;

  const float sm_scale = 0.08838834764831845f;  // 1/sqrt(128)
  const _Float16* kbase = kq + (long)bh * S_LEN * D_HEAD;
  const _Float16* vbase = vt + (long)bh * D_HEAD * S_LEN;

  // register prefetch buffers (4x16B K + 4x16B V per thread = one tile)
  half8 kpre[4], vpre[4];
  {
    int j0 = t_lo * 64;
    #pragma unroll
    for (int c = 0; c < 4; ++c) {
      int chunk = t + c * 256;
      kpre[c] = *(const half8*)(kbase + (long)(j0 + (chunk >> 4)) * D_HEAD + (chunk & 15) * 8);
      vpre[c] = *(const half8*)(vbase + (long)(chunk >> 3) * S_LEN + j0 + (chunk & 7) * 8);
    }
  }

  for (int tt = t_lo; tt <= t_hi; ++tt) {
    int j0 = tt * 64;
    __syncthreads();                       // prev tile's LDS reads done
    #pragma unroll
    for (int c = 0; c < 4; ++c) {
      int chunk = t + c * 256;
      *(half8*)(Kl + (chunk >> 4) * 136 + (chunk & 15) * 8) = kpre[c];
      *(half8*)(Vl + (chunk >> 3) * 72 + (chunk & 7) * 8) = vpre[c];
    }
    __syncthreads();
    if (tt < t_hi) {                       // issue next tile's loads early
      int j1 = j0 + 64;
      #pragma unroll
      for (int c = 0; c < 4; ++c) {
        int chunk = t + c * 256;
        kpre[c] = *(const half8*)(kbase + (long)(j1 + (chunk >> 4)) * D_HEAD + (chunk & 15) * 8);
        vpre[c] = *(const half8*)(vbase + (long)(chunk >> 3) * S_LEN + j1 + (chunk & 7) * 8);
      }
    }

    // wave-uniform skip: tile outside this wave's window
    if (j0 + 63 < r0 - wl || j0 > r0 + 15 + wr) continue;

    float dscale = qs * kscale[bh * 32 + tt] * sm_scale;
    bool need_mask = (j0 < r0 + 15 - wl) || (j0 + 63 > r0 + wr);

    // S = Q K^T (int8-exact in f16 MFMA)
    floatx4 sacc[4];
    #pragma unroll
    for (int nb = 0; nb < 4; ++nb) sacc[nb] = (floatx4){0.f,0.f,0.f,0.f};
    #pragma unroll
    for (int nb = 0; nb < 4; ++nb)
      #pragma unroll
      for (int ks = 0; ks < 4; ++ks) {
        half8 bfr = *(const half8*)(Kl + (nb * 16 + ln) * 136 + ks * 32 + qd * 8);
        sacc[nb] = __builtin_amdgcn_mfma_f32_16x16x32_f16(qa[ks], bfr, sacc[nb], 0, 0, 0);
      }

    // dequant + mask + online softmax (C layout: col=ln, row=qd*4+r)
    float p[4][4], alpha[4];
    #pragma unroll
    for (int r = 0; r < 4; ++r) {
      int row = r0 + qd * 4 + r;
      float sv[4], mx = -1e30f;
      #pragma unroll
      for (int nb = 0; nb < 4; ++nb) {
        float s = sacc[nb][r] * dscale;
        if (need_mask) {
          int col = j0 + nb * 16 + ln;
          bool ok = (row - col <= wl) && (col - row <= wr);
          s = ok ? s : -1e30f;
        }
        sv[nb] = s;
        mx = fmaxf(mx, s);
      }
      #pragma unroll
      for (int off = 1; off < 16; off <<= 1)
        mx = fmaxf(mx, __shfl_xor(mx, off, 64));
      float mnew = fmaxf(mrow[r], mx);
      float a = __expf(mrow[r] - mnew);
      float rs = 0.f;
      #pragma unroll
      for (int nb = 0; nb < 4; ++nb) {
        float pv = __expf(sv[nb] - mnew);
        p[r][nb] = pv;
        rs += pv;
      }
      #pragma unroll
      for (int off = 1; off < 16; off <<= 1)
        rs += __shfl_xor(rs, off, 64);
      mrow[r] = mnew;
      lrow[r] = lrow[r] * a + rs;
      alpha[r] = a;
    }

    // rescale O
    #pragma unroll
    for (int nd = 0; nd < 8; ++nd) {
      floatx4 o = oacc[nd];
      #pragma unroll
      for (int r = 0; r < 4; ++r) o[r] *= alpha[r];
      oacc[nd] = o;
    }

    // P: C layout -> fp16 -> per-wave LDS -> A layout
    _Float16* pw = Pl[wv];
    #pragma unroll
    for (int r = 0; r < 4; ++r)
      #pragma unroll
      for (int nb = 0; nb < 4; ++nb)
        pw[(qd * 4 + r) * 68 + nb * 16 + ln] = (_Float16)p[r][nb];
    __threadfence_block();
    half8 pa[2];
    #pragma unroll
    for (int ks = 0; ks < 2; ++ks)
      pa[ks] = *(const half8*)(pw + ln * 68 + ks * 32 + qd * 8);

    // O += P Vhat
    #pragma unroll
    for (int nd = 0; nd < 8; ++nd)
      #pragma unroll
      for (int ks = 0; ks < 2; ++ks) {
        half8 bfr = *(const half8*)(Vl + (nd * 16 + ln) * 72 + ks * 32 + qd * 8);
        oacc[nd] = __builtin_amdgcn_mfma_f32_16x16x32_f16(pa[ks], bfr, oacc[nd], 0, 0, 0);
      }
  }

  // epilogue: out = fp16(O/l) + v_mean
  float vm[8];
  #pragma unroll
  for (int nd = 0; nd < 8; ++nd)
    vm[nd] = vsum[bh * D_HEAD + nd * 16 + ln] * (1.0f / 2048.0f);
  float* obase = out + ((long)b * S_LEN) * NHID + h * D_HEAD;
  #pragma unroll
  for (int r = 0; r < 4; ++r) {
    int row = r0 + qd * 4 + r;
    float linv = 1.0f / lrow[r];
    #pragma unroll
    for (int nd = 0; nd < 8; ++nd) {
      float o16 = (float)(_Float16)(oacc[nd][r] * linv);
      obase[(long)row * NHID + nd * 16 + ln] = o16 + vm[nd];
    }
  }
}

extern "C" void kernel_launch(void* const* d_in, const int* in_sizes, int n_in,
                              void* d_out, int out_size, void* d_ws, size_t ws_size,
                              hipStream_t stream) {
  (void)in_sizes; (void)n_in; (void)out_size; (void)ws_size;
  const float* q = (const float*)d_in[0];
  const float* k = (const float*)d_in[1];
  const float* v = (const float*)d_in[2];
  const int* wl = (const int*)d_in[3];
  const int* wr = (const int*)d_in[4];
  float* out = (float*)d_out;

  char* ws = (char*)d_ws;
  size_t off = 0;
  const size_t tensz = (size_t)N_BH * S_LEN * D_HEAD * sizeof(_Float16);  // 16.78 MB
  _Float16* qq = (_Float16*)(ws + off); off += tensz;
  _Float16* kq = (_Float16*)(ws + off); off += tensz;
  _Float16* vt = (_Float16*)(ws + off); off += tensz;
  float* ksum   = (float*)(ws + off); off += N_BH * D_HEAD * sizeof(float);
  float* vsum   = (float*)(ws + off); off += N_BH * D_HEAD * sizeof(float);
  float* qscale = (float*)(ws + off); off += N_BH * 64 * sizeof(float);
  float* kscale = (float*)(ws + off); off += N_BH * 32 * sizeof(float);

  hipMemsetAsync(ksum, 0, 2 * N_BH * D_HEAD * sizeof(float), stream);
  means_kernel<<<512, 256, 0, stream>>>(k, v, ksum, vsum);
  prep_kernel<<<4096, 256, 0, stream>>>(q, k, v, ksum, vsum, qq, kq, vt, qscale, kscale);
  attn_kernel<<<1024, 256, 0, stream>>>(qq, kq, vt, qscale, kscale, vsum, wl, wr, out);
}